// Round 6
// baseline (861.152 us; speedup 1.0000x reference)
//
#include <hip/hip_runtime.h>
#include <hip/hip_bf16.h>

// GCN (3-layer, JK=sum) on MI355X.
// R6: CSR build via 2-phase bucket binning (dst>>6, 64 rows/bucket):
//     k_bin appends packed (src<<6|dstlo) per-bucket (sequential stream writes,
//     ~2x HBM amp), k_csr builds rowptr/dinv/col per-bucket with LDS counts+
//     cursors (col writes stay in a 4KB line-resident window).
//     Replaces k_count+k_scanA/B/C+k_dinv+k_fill (fill alone: 105MB writes, 130us).

constexpr int NN = 100000;
constexpr int EE = 1600000;
constexpr int DD = 128;
constexpr float BN_EPS = 1e-5f;
constexpr int NPAD = 100096;
constexpr int SPMM_GRID = NN / 16;              // 6250
constexpr int NB = (NN + 63) / 64;              // 1563 buckets
constexpr int CAP = 1536;                       // mean 1024, sigma~32 -> 16 sigma

__device__ __forceinline__ float bfhi(unsigned int u) {
  union { unsigned int i; float f; } v; v.i = u & 0xffff0000u; return v.f;
}
__device__ __forceinline__ float bflo(unsigned int u) {
  union { unsigned int i; float f; } v; v.i = u << 16; return v.f;
}
__device__ __forceinline__ unsigned short f2bf(float f) {
  union { float f; unsigned int i; } v;
  v.f = f;
  unsigned int r = v.i + 0x7FFFu + ((v.i >> 16) & 1u);   // RNE
  return (unsigned short)(r >> 16);
}
__device__ __forceinline__ void acc8(uint4 u, float4& a0, float4& a1) {
  a0.x += bflo(u.x); a0.y += bfhi(u.x);
  a0.z += bflo(u.y); a0.w += bfhi(u.y);
  a1.x += bflo(u.z); a1.y += bfhi(u.z);
  a1.z += bflo(u.w); a1.w += bfhi(u.w);
}

// Phase 1: bin edges by dst>>6. bcnt padded to 16 ints (64B) per bucket.
__global__ void k_bin(const int* __restrict__ src, const int* __restrict__ dst,
                      int* __restrict__ bcnt, unsigned* __restrict__ bstore) {
  int e = blockIdx.x * 256 + threadIdx.x;
  if (e < EE) {
    const int d = dst[e];
    const int s = src[e];
    const int b = d >> 6;
    const int pos = atomicAdd(&bcnt[b * 16], 1);
    if (pos < CAP)
      bstore[(size_t)b * CAP + pos] = ((unsigned)s << 6) | (unsigned)(d & 63);
  }
}

// Phase 2a: exclusive scan of bucket totals
__global__ __launch_bounds__(1024)
void k_bscan(const int* __restrict__ bcnt, int* __restrict__ bbase) {
  __shared__ int part[1024];
  const int t = threadIdx.x;
  const int i0 = t * 2;
  const int v0 = (i0 < NB) ? bcnt[i0 * 16] : 0;
  const int v1 = (i0 + 1 < NB) ? bcnt[(i0 + 1) * 16] : 0;
  const int sum = v0 + v1;
  part[t] = sum;
  __syncthreads();
  for (int off = 1; off < 1024; off <<= 1) {
    int x = (t >= off) ? part[t - off] : 0;
    __syncthreads();
    part[t] += x;
    __syncthreads();
  }
  const int base = part[t] - sum;      // exclusive
  if (i0 < NB) bbase[i0] = base;
  if (i0 + 1 < NB) bbase[i0 + 1] = base + v0;
}

// Phase 2b: per-bucket CSR build. LDS counts -> rowptr/dinv; LDS cursors -> col.
__global__ __launch_bounds__(256)
void k_csr(const unsigned* __restrict__ bstore, const int* __restrict__ bcnt,
           const int* __restrict__ bbase, int* __restrict__ rowptr,
           int* __restrict__ col, float* __restrict__ dinv) {
  __shared__ int lcnt[64], lpre[64], lcur[64];
  const int b = blockIdx.x;
  const int t = threadIdx.x;
  const int n = min(bcnt[b * 16], CAP);
  const int base = bbase[b];
  if (t < 64) lcnt[t] = 0;
  __syncthreads();
  const unsigned* bs = &bstore[(size_t)b * CAP];
  for (int i = t; i < n; i += 256) atomicAdd(&lcnt[bs[i] & 63u], 1);
  __syncthreads();
  if (t == 0) {
    int run = 0;
    for (int r = 0; r < 64; ++r) { lpre[r] = run; run += lcnt[r]; }
  }
  __syncthreads();
  if (t < 64) {
    lcur[t] = lpre[t];
    const int row = b * 64 + t;
    if (row < NN) {
      rowptr[row] = base + lpre[t];
      dinv[row] = rsqrtf((float)lcnt[t] + 1.0f);
    }
  }
  if (b == 0 && t == 0) rowptr[NN] = EE;
  __syncthreads();
  for (int i = t; i < n; i += 256) {
    const unsigned e = bs[i];
    const int p = atomicAdd(&lcur[e & 63u], 1);
    col[base + p] = (int)(e >> 6);
  }
}

// hs[r][c] = bf16( dinv[r] * sum_k h[r][k] * W[k][c] )
__global__ __launch_bounds__(256, 2)
void k_gemm(const float* __restrict__ h, const float* __restrict__ Wl,
            const float* __restrict__ dinv, unsigned short* __restrict__ hsb) {
  __shared__ float Wlds[DD * DD];      // 64 KB
  for (int i = threadIdx.x; i < DD * DD; i += 256) Wlds[i] = Wl[i];
  __syncthreads();
  const int lane = threadIdx.x & 31;
  const int g = threadIdx.x >> 5;      // 0..7
  const int c4 = lane * 4;
  const int rbase = blockIdx.x * 64 + g * 8;
  if (rbase >= NN) return;
  float4 acc[8];
#pragma unroll
  for (int i = 0; i < 8; ++i) acc[i] = make_float4(0.f, 0.f, 0.f, 0.f);
  const bool full = (rbase + 8 <= NN);
  for (int k = 0; k < DD; k += 4) {
    float4 hv[8];
    if (full) {
#pragma unroll
      for (int i = 0; i < 8; ++i)
        hv[i] = *(const float4*)&h[(size_t)(rbase + i) * DD + k];
    } else {
#pragma unroll
      for (int i = 0; i < 8; ++i)
        hv[i] = (rbase + i < NN)
                    ? *(const float4*)&h[(size_t)(rbase + i) * DD + k]
                    : make_float4(0.f, 0.f, 0.f, 0.f);
    }
    const float4 w0 = *(const float4*)&Wlds[(k + 0) * DD + c4];
    const float4 w1 = *(const float4*)&Wlds[(k + 1) * DD + c4];
    const float4 w2 = *(const float4*)&Wlds[(k + 2) * DD + c4];
    const float4 w3 = *(const float4*)&Wlds[(k + 3) * DD + c4];
#pragma unroll
    for (int i = 0; i < 8; ++i) {
      acc[i].x = fmaf(hv[i].x, w0.x, acc[i].x);
      acc[i].x = fmaf(hv[i].y, w1.x, acc[i].x);
      acc[i].x = fmaf(hv[i].z, w2.x, acc[i].x);
      acc[i].x = fmaf(hv[i].w, w3.x, acc[i].x);
      acc[i].y = fmaf(hv[i].x, w0.y, acc[i].y);
      acc[i].y = fmaf(hv[i].y, w1.y, acc[i].y);
      acc[i].y = fmaf(hv[i].z, w2.y, acc[i].y);
      acc[i].y = fmaf(hv[i].w, w3.y, acc[i].y);
      acc[i].z = fmaf(hv[i].x, w0.z, acc[i].z);
      acc[i].z = fmaf(hv[i].y, w1.z, acc[i].z);
      acc[i].z = fmaf(hv[i].z, w2.z, acc[i].z);
      acc[i].z = fmaf(hv[i].w, w3.z, acc[i].z);
      acc[i].w = fmaf(hv[i].x, w0.w, acc[i].w);
      acc[i].w = fmaf(hv[i].y, w1.w, acc[i].w);
      acc[i].w = fmaf(hv[i].z, w2.w, acc[i].w);
      acc[i].w = fmaf(hv[i].w, w3.w, acc[i].w);
    }
  }
#pragma unroll
  for (int i = 0; i < 8; ++i) {
    int r = rbase + i;
    if (r < NN) {
      float dv = dinv[r];
      ushort4 o4;
      o4.x = f2bf(acc[i].x * dv);
      o4.y = f2bf(acc[i].y * dv);
      o4.z = f2bf(acc[i].z * dv);
      o4.w = f2bf(acc[i].w * dv);
      *(ushort4*)&hsb[(size_t)r * DD + c4] = o4;
    }
  }
}

// 16 lanes per dst row, 16 rows per block, 4-deep gather unroll.
// mode 0: hout = relu(dinv*(sum+self)+b); per-block BN partials
// mode 1: out += relu(...)
__global__ __launch_bounds__(256)
void k_spmm(const unsigned short* __restrict__ hsb, const int* __restrict__ rowptr,
            const int* __restrict__ col, const float* __restrict__ dinv,
            const float* __restrict__ bias, float* __restrict__ hout,
            float* __restrict__ out, float* __restrict__ partials,
            const int mode) {
  const int lane = threadIdx.x & 15;     // 16 lanes / row
  const int g = threadIdx.x >> 4;        // 0..15 rows / block
  const int c8 = lane * 8;
  const int d = blockIdx.x * 16 + g;
  float4 a0 = make_float4(0.f, 0.f, 0.f, 0.f);
  float4 a1 = make_float4(0.f, 0.f, 0.f, 0.f);
  float4 bs0 = a0, bs1 = a0, q0 = a0, q1 = a0;
  if (d < NN) {
    const unsigned short* rowp = &hsb[(size_t)d * DD + c8];
    acc8(*(const uint4*)rowp, a0, a1);                 // self-loop term
    int j = rowptr[d];
    const int e1 = rowptr[d + 1];
    for (; j + 3 < e1; j += 4) {
      const int s0 = col[j], s1 = col[j + 1], s2 = col[j + 2], s3 = col[j + 3];
      const uint4 u0 = *(const uint4*)&hsb[(size_t)s0 * DD + c8];
      const uint4 u1 = *(const uint4*)&hsb[(size_t)s1 * DD + c8];
      const uint4 u2 = *(const uint4*)&hsb[(size_t)s2 * DD + c8];
      const uint4 u3 = *(const uint4*)&hsb[(size_t)s3 * DD + c8];
      acc8(u0, a0, a1); acc8(u1, a0, a1);
      acc8(u2, a0, a1); acc8(u3, a0, a1);
    }
    for (; j < e1; ++j) {
      const uint4 u0 = *(const uint4*)&hsb[(size_t)col[j] * DD + c8];
      acc8(u0, a0, a1);
    }
    const float dv = dinv[d];
    const float4 b0 = *(const float4*)&bias[c8];
    const float4 b1 = *(const float4*)&bias[c8 + 4];
    float4 o0, o1;
    o0.x = fmaxf(fmaf(a0.x, dv, b0.x), 0.f);
    o0.y = fmaxf(fmaf(a0.y, dv, b0.y), 0.f);
    o0.z = fmaxf(fmaf(a0.z, dv, b0.z), 0.f);
    o0.w = fmaxf(fmaf(a0.w, dv, b0.w), 0.f);
    o1.x = fmaxf(fmaf(a1.x, dv, b1.x), 0.f);
    o1.y = fmaxf(fmaf(a1.y, dv, b1.y), 0.f);
    o1.z = fmaxf(fmaf(a1.z, dv, b1.z), 0.f);
    o1.w = fmaxf(fmaf(a1.w, dv, b1.w), 0.f);
    if (mode == 0) {
      *(float4*)&hout[(size_t)d * DD + c8] = o0;
      *(float4*)&hout[(size_t)d * DD + c8 + 4] = o1;
      bs0 = o0; bs1 = o1;
      q0.x = o0.x * o0.x; q0.y = o0.y * o0.y;
      q0.z = o0.z * o0.z; q0.w = o0.w * o0.w;
      q1.x = o1.x * o1.x; q1.y = o1.y * o1.y;
      q1.z = o1.z * o1.z; q1.w = o1.w * o1.w;
    } else {
      float4 p0 = *(const float4*)&out[(size_t)d * DD + c8];
      float4 p1 = *(const float4*)&out[(size_t)d * DD + c8 + 4];
      p0.x += o0.x; p0.y += o0.y; p0.z += o0.z; p0.w += o0.w;
      p1.x += o1.x; p1.y += o1.y; p1.z += o1.z; p1.w += o1.w;
      *(float4*)&out[(size_t)d * DD + c8] = p0;
      *(float4*)&out[(size_t)d * DD + c8 + 4] = p1;
    }
  }
  if (mode == 0) {
    __shared__ float red[256 * 16];
    float* my = &red[threadIdx.x * 16];
    my[0] = bs0.x; my[1] = bs0.y; my[2] = bs0.z; my[3] = bs0.w;
    my[4] = bs1.x; my[5] = bs1.y; my[6] = bs1.z; my[7] = bs1.w;
    my[8] = q0.x;  my[9] = q0.y;  my[10] = q0.z; my[11] = q0.w;
    my[12] = q1.x; my[13] = q1.y; my[14] = q1.z; my[15] = q1.w;
    __syncthreads();
    const int t = threadIdx.x;
    float s = 0.f;
#pragma unroll
    for (int gg = 0; gg < 16; ++gg) s += red[gg * 256 + t];
    partials[(size_t)t * SPMM_GRID + blockIdx.x] = s;
  }
}

// one block per slot: stat[slot] = sum over blocks of partials[slot][*]
__global__ __launch_bounds__(256)
void k_bnred(const float* __restrict__ partials, float* __restrict__ stat) {
  __shared__ float s[256];
  const int slot = blockIdx.x;
  float v = 0.f;
  for (int i = threadIdx.x; i < SPMM_GRID; i += 256)
    v += partials[(size_t)slot * SPMM_GRID + i];
  s[threadIdx.x] = v;
  __syncthreads();
  for (int off = 128; off; off >>= 1) {
    if (threadIdx.x < off) s[threadIdx.x] += s[threadIdx.x + off];
    __syncthreads();
  }
  if (threadIdx.x == 0) stat[slot] = s[0];
}

// stat[256] -> per-channel scale/shift.  slot = lane16*16+q
__global__ __launch_bounds__(256)
void k_bnfin(const float* __restrict__ stat, float* __restrict__ ss,
             const float* __restrict__ gamma, const float* __restrict__ beta) {
  __shared__ float tot[256];            // [kind*128 + c]
  const int t = threadIdx.x;
  const float s = stat[t];
  const int lane16 = t >> 4, q = t & 15;
  const int c = lane16 * 8 + (q & 7), kind = q >> 3;
  tot[kind * 128 + c] = s;
  __syncthreads();
  if (t < 128) {
    const float m = tot[t] * (1.0f / NN);
    const float var = tot[128 + t] * (1.0f / NN) - m * m;
    const float rs = rsqrtf(var + BN_EPS);
    const float sc = rs * gamma[t];
    ss[t] = sc;
    ss[128 + t] = beta[t] - m * sc;
  }
}

// h = h*scale + shift (in place); out += h
__global__ __launch_bounds__(256)
void k_bn(float* __restrict__ h, float* __restrict__ out,
          const float* __restrict__ ss) {
  const int i4 = blockIdx.x * 256 + threadIdx.x;   // exactly N*D/4 threads
  const int c4 = (i4 & 31) * 4;
  const float4 sc = *(const float4*)&ss[c4];
  const float4 sh = *(const float4*)&ss[128 + c4];
  float4 hv = ((const float4*)h)[i4];
  float4 o;
  o.x = fmaf(hv.x, sc.x, sh.x);
  o.y = fmaf(hv.y, sc.y, sh.y);
  o.z = fmaf(hv.z, sc.z, sh.z);
  o.w = fmaf(hv.w, sc.w, sh.w);
  ((float4*)h)[i4] = o;
  float4 po = ((float4*)out)[i4];
  po.x += o.x; po.y += o.y; po.z += o.z; po.w += o.w;
  ((float4*)out)[i4] = po;
}

extern "C" void kernel_launch(void* const* d_in, const int* in_sizes, int n_in,
                              void* d_out, int out_size, void* d_ws, size_t ws_size,
                              hipStream_t stream) {
  const float* x = (const float*)d_in[0];
  const int* ei = (const int*)d_in[1];
  const float* W = (const float*)d_in[2];
  const float* b = (const float*)d_in[3];
  const float* gamma = (const float*)d_in[4];
  const float* beta = (const float*)d_in[5];
  float* out = (float*)d_out;
  const int* srcv = ei;
  const int* dstv = ei + EE;

  char* w = (char*)d_ws;
  int* rowptr = (int*)w;     w += (size_t)NPAD * 4;
  float* dinv = (float*)w;   w += (size_t)NPAD * 4;
  int* bcnt = (int*)w;       w += (size_t)NB * 16 * 4;     // 64B-padded cursors
  int* bbase = (int*)w;      w += (size_t)2048 * 4;
  int* col = (int*)w;        w += (size_t)EE * 4;
  float* ss = (float*)w;     w += 256 * 4;
  float* stat = (float*)w;   w += 256 * 4;
  // bstore (phase 1/2 only) aliases partials (spmm/bnred only) — disjoint lifetimes
  unsigned* bstore = (unsigned*)w;
  float* partials = (float*)w; w += (size_t)NB * CAP * 4;  // 9.6 MB >= 6.4 MB
  float* bufA = (float*)w;   w += (size_t)NN * DD * 4;     // h (fp32)
  unsigned short* hsb = (unsigned short*)w;                // hs (bf16)

  hipMemsetAsync(bcnt, 0, (size_t)NB * 16 * 4, stream);
  hipMemcpyAsync(out, x, (size_t)NN * DD * sizeof(float),
                 hipMemcpyDeviceToDevice, stream);

  k_bin<<<(EE + 255) / 256, 256, 0, stream>>>(srcv, dstv, bcnt, bstore);
  k_bscan<<<1, 1024, 0, stream>>>(bcnt, bbase);
  k_csr<<<NB, 256, 0, stream>>>(bstore, bcnt, bbase, rowptr, col, dinv);

  const float* hcur = x;
  for (int l = 0; l < 3; ++l) {
    k_gemm<<<(NN + 63) / 64, 256, 0, stream>>>(hcur, W + (size_t)l * DD * DD,
                                               dinv, hsb);
    if (l < 2) {
      k_spmm<<<SPMM_GRID, 256, 0, stream>>>(hsb, rowptr, col, dinv,
                                            b + l * DD, bufA, nullptr,
                                            partials, 0);
      k_bnred<<<256, 256, 0, stream>>>(partials, stat);
      k_bnfin<<<1, 256, 0, stream>>>(stat, ss, gamma + l * DD, beta + l * DD);
      k_bn<<<(NN * DD / 4) / 256, 256, 0, stream>>>(bufA, out, ss);
      hcur = bufA;
    } else {
      k_spmm<<<SPMM_GRID, 256, 0, stream>>>(hsb, rowptr, col, dinv,
                                            b + l * DD, nullptr, out,
                                            nullptr, 1);
    }
  }
}

// Round 7
// 757.527 us; speedup vs baseline: 1.1368x; 1.1368x over previous
//
#include <hip/hip_runtime.h>
#include <hip/hip_bf16.h>

// GCN (3-layer, JK=sum) on MI355X.
// R7: GEMM -> MFMA bf16 (v_mfma_f32_16x16x32_bf16). 4 waves/block, 64 rows/
//     block, wave = 16 rows x 128 cols (8 col-tiles, 32 VGPR acc). A from fp32
//     h (cvt in regs), B from pre-transposed bf16 Wt[c][k] (32KB, cache-
//     resident). Replaces ~100us/layer fp32 VALU GEMM (~33TF) with ~5us MFMA
//     compute + h-stream. Layouts per m89: A[m=lane&15][k=quad*8+j],
//     B[k=quad*8+j][n=lane&15], D col=lane&15 row=quad*4+reg.

constexpr int NN = 100000;
constexpr int EE = 1600000;
constexpr int DD = 128;
constexpr float BN_EPS = 1e-5f;
constexpr int NPAD = 100096;
constexpr int SPMM_GRID = NN / 16;              // 6250
constexpr int NB = (NN + 63) / 64;              // 1563 buckets
constexpr int CAP = 1536;
constexpr int GEMM_GRID = (NN + 63) / 64;       // 1563

typedef __attribute__((ext_vector_type(8))) short bf16x8;
typedef __attribute__((ext_vector_type(4))) float f32x4;

__device__ __forceinline__ float bfhi(unsigned int u) {
  union { unsigned int i; float f; } v; v.i = u & 0xffff0000u; return v.f;
}
__device__ __forceinline__ float bflo(unsigned int u) {
  union { unsigned int i; float f; } v; v.i = u << 16; return v.f;
}
__device__ __forceinline__ unsigned short f2bf(float f) {
  union { float f; unsigned int i; } v;
  v.f = f;
  unsigned int r = v.i + 0x7FFFu + ((v.i >> 16) & 1u);   // RNE
  return (unsigned short)(r >> 16);
}
__device__ __forceinline__ void acc8(uint4 u, float4& a0, float4& a1) {
  a0.x += bflo(u.x); a0.y += bfhi(u.x);
  a0.z += bflo(u.y); a0.w += bfhi(u.y);
  a1.x += bflo(u.z); a1.y += bfhi(u.z);
  a1.z += bflo(u.w); a1.w += bfhi(u.w);
}

// --- CSR build (R6 structure; k_bin rework deferred to next round) ---

__global__ void k_bin(const int* __restrict__ src, const int* __restrict__ dst,
                      int* __restrict__ bcnt, unsigned* __restrict__ bstore) {
  int e = blockIdx.x * 256 + threadIdx.x;
  if (e < EE) {
    const int d = dst[e];
    const int s = src[e];
    const int b = d >> 6;
    const int pos = atomicAdd(&bcnt[b * 16], 1);
    if (pos < CAP)
      bstore[(size_t)b * CAP + pos] = ((unsigned)s << 6) | (unsigned)(d & 63);
  }
}

__global__ __launch_bounds__(1024)
void k_bscan(const int* __restrict__ bcnt, int* __restrict__ bbase) {
  __shared__ int part[1024];
  const int t = threadIdx.x;
  const int i0 = t * 2;
  const int v0 = (i0 < NB) ? bcnt[i0 * 16] : 0;
  const int v1 = (i0 + 1 < NB) ? bcnt[(i0 + 1) * 16] : 0;
  const int sum = v0 + v1;
  part[t] = sum;
  __syncthreads();
  for (int off = 1; off < 1024; off <<= 1) {
    int x = (t >= off) ? part[t - off] : 0;
    __syncthreads();
    part[t] += x;
    __syncthreads();
  }
  const int base = part[t] - sum;      // exclusive
  if (i0 < NB) bbase[i0] = base;
  if (i0 + 1 < NB) bbase[i0 + 1] = base + v0;
}

__global__ __launch_bounds__(256)
void k_csr(const unsigned* __restrict__ bstore, const int* __restrict__ bcnt,
           const int* __restrict__ bbase, int* __restrict__ rowptr,
           int* __restrict__ col, float* __restrict__ dinv) {
  __shared__ int lcnt[64], lpre[64], lcur[64];
  const int b = blockIdx.x;
  const int t = threadIdx.x;
  const int n = min(bcnt[b * 16], CAP);
  const int base = bbase[b];
  if (t < 64) lcnt[t] = 0;
  __syncthreads();
  const unsigned* bs = &bstore[(size_t)b * CAP];
  for (int i = t; i < n; i += 256) atomicAdd(&lcnt[bs[i] & 63u], 1);
  __syncthreads();
  if (t == 0) {
    int run = 0;
    for (int r = 0; r < 64; ++r) { lpre[r] = run; run += lcnt[r]; }
  }
  __syncthreads();
  if (t < 64) {
    lcur[t] = lpre[t];
    const int row = b * 64 + t;
    if (row < NN) {
      rowptr[row] = base + lpre[t];
      dinv[row] = rsqrtf((float)lcnt[t] + 1.0f);
    }
  }
  if (b == 0 && t == 0) rowptr[NN] = EE;
  __syncthreads();
  for (int i = t; i < n; i += 256) {
    const unsigned e = bs[i];
    const int p = atomicAdd(&lcur[e & 63u], 1);
    col[base + p] = (int)(e >> 6);
  }
}

// --- W transpose+cvt: Wt[l][c][k] = bf16(W[l][k][c]) --- grid = 3 blocks
__global__ __launch_bounds__(256)
void k_wt(const float* __restrict__ W, unsigned short* __restrict__ Wt) {
  const float* Ws = W + (size_t)blockIdx.x * DD * DD;
  unsigned short* Wo = Wt + (size_t)blockIdx.x * DD * DD;
  for (int i = threadIdx.x; i < DD * DD; i += 256) {
    const int k = i >> 7, c = i & 127;
    Wo[c * DD + k] = f2bf(Ws[i]);
  }
}

// --- MFMA GEMM: hsb[r][c] = bf16( dinv[r] * sum_k h[r][k] * W[k][c] ) ---
__global__ __launch_bounds__(256)
void k_gemm(const float* __restrict__ h, const unsigned short* __restrict__ Wt,
            const float* __restrict__ dinv, unsigned short* __restrict__ hsb) {
  const int lane = threadIdx.x & 63;
  const int wave = threadIdx.x >> 6;          // 0..3
  const int n15 = lane & 15;
  const int quad = lane >> 4;                 // 0..3
  const int rbase = blockIdx.x * 64 + wave * 16;
  const int arow = min(rbase + n15, NN - 1);  // A-load row (clamped; stores guarded)

  f32x4 acc[8];
#pragma unroll
  for (int ct = 0; ct < 8; ++ct) acc[ct] = (f32x4){0.f, 0.f, 0.f, 0.f};

#pragma unroll
  for (int kc = 0; kc < 4; ++kc) {
    const int k0 = kc * 32 + quad * 8;
    const float4 a0 = *(const float4*)&h[(size_t)arow * DD + k0];
    const float4 a1 = *(const float4*)&h[(size_t)arow * DD + k0 + 4];
    bf16x8 af;
    af[0] = (short)f2bf(a0.x); af[1] = (short)f2bf(a0.y);
    af[2] = (short)f2bf(a0.z); af[3] = (short)f2bf(a0.w);
    af[4] = (short)f2bf(a1.x); af[5] = (short)f2bf(a1.y);
    af[6] = (short)f2bf(a1.z); af[7] = (short)f2bf(a1.w);
#pragma unroll
    for (int ct = 0; ct < 8; ++ct) {
      const bf16x8 bf = *(const bf16x8*)&Wt[(size_t)(ct * 16 + n15) * DD + k0];
      acc[ct] = __builtin_amdgcn_mfma_f32_16x16x32_bf16(af, bf, acc[ct], 0, 0, 0);
    }
  }

#pragma unroll
  for (int i = 0; i < 4; ++i) {
    const int r = rbase + quad * 4 + i;
    if (r < NN) {
      const float dv = dinv[r];
#pragma unroll
      for (int ct = 0; ct < 8; ++ct)
        hsb[(size_t)r * DD + ct * 16 + n15] = f2bf(acc[ct][i] * dv);
    }
  }
}

// --- SpMM (unchanged from R6) ---
__global__ __launch_bounds__(256)
void k_spmm(const unsigned short* __restrict__ hsb, const int* __restrict__ rowptr,
            const int* __restrict__ col, const float* __restrict__ dinv,
            const float* __restrict__ bias, float* __restrict__ hout,
            float* __restrict__ out, float* __restrict__ partials,
            const int mode) {
  const int lane = threadIdx.x & 15;     // 16 lanes / row
  const int g = threadIdx.x >> 4;        // 0..15 rows / block
  const int c8 = lane * 8;
  const int d = blockIdx.x * 16 + g;
  float4 a0 = make_float4(0.f, 0.f, 0.f, 0.f);
  float4 a1 = make_float4(0.f, 0.f, 0.f, 0.f);
  float4 bs0 = a0, bs1 = a0, q0 = a0, q1 = a0;
  if (d < NN) {
    const unsigned short* rowp = &hsb[(size_t)d * DD + c8];
    acc8(*(const uint4*)rowp, a0, a1);                 // self-loop term
    int j = rowptr[d];
    const int e1 = rowptr[d + 1];
    for (; j + 3 < e1; j += 4) {
      const int s0 = col[j], s1 = col[j + 1], s2 = col[j + 2], s3 = col[j + 3];
      const uint4 u0 = *(const uint4*)&hsb[(size_t)s0 * DD + c8];
      const uint4 u1 = *(const uint4*)&hsb[(size_t)s1 * DD + c8];
      const uint4 u2 = *(const uint4*)&hsb[(size_t)s2 * DD + c8];
      const uint4 u3 = *(const uint4*)&hsb[(size_t)s3 * DD + c8];
      acc8(u0, a0, a1); acc8(u1, a0, a1);
      acc8(u2, a0, a1); acc8(u3, a0, a1);
    }
    for (; j < e1; ++j) {
      const uint4 u0 = *(const uint4*)&hsb[(size_t)col[j] * DD + c8];
      acc8(u0, a0, a1);
    }
    const float dv = dinv[d];
    const float4 b0 = *(const float4*)&bias[c8];
    const float4 b1 = *(const float4*)&bias[c8 + 4];
    float4 o0, o1;
    o0.x = fmaxf(fmaf(a0.x, dv, b0.x), 0.f);
    o0.y = fmaxf(fmaf(a0.y, dv, b0.y), 0.f);
    o0.z = fmaxf(fmaf(a0.z, dv, b0.z), 0.f);
    o0.w = fmaxf(fmaf(a0.w, dv, b0.w), 0.f);
    o1.x = fmaxf(fmaf(a1.x, dv, b1.x), 0.f);
    o1.y = fmaxf(fmaf(a1.y, dv, b1.y), 0.f);
    o1.z = fmaxf(fmaf(a1.z, dv, b1.z), 0.f);
    o1.w = fmaxf(fmaf(a1.w, dv, b1.w), 0.f);
    if (mode == 0) {
      *(float4*)&hout[(size_t)d * DD + c8] = o0;
      *(float4*)&hout[(size_t)d * DD + c8 + 4] = o1;
      bs0 = o0; bs1 = o1;
      q0.x = o0.x * o0.x; q0.y = o0.y * o0.y;
      q0.z = o0.z * o0.z; q0.w = o0.w * o0.w;
      q1.x = o1.x * o1.x; q1.y = o1.y * o1.y;
      q1.z = o1.z * o1.z; q1.w = o1.w * o1.w;
    } else {
      float4 p0 = *(const float4*)&out[(size_t)d * DD + c8];
      float4 p1 = *(const float4*)&out[(size_t)d * DD + c8 + 4];
      p0.x += o0.x; p0.y += o0.y; p0.z += o0.z; p0.w += o0.w;
      p1.x += o1.x; p1.y += o1.y; p1.z += o1.z; p1.w += o1.w;
      *(float4*)&out[(size_t)d * DD + c8] = p0;
      *(float4*)&out[(size_t)d * DD + c8 + 4] = p1;
    }
  }
  if (mode == 0) {
    __shared__ float red[256 * 16];
    float* my = &red[threadIdx.x * 16];
    my[0] = bs0.x; my[1] = bs0.y; my[2] = bs0.z; my[3] = bs0.w;
    my[4] = bs1.x; my[5] = bs1.y; my[6] = bs1.z; my[7] = bs1.w;
    my[8] = q0.x;  my[9] = q0.y;  my[10] = q0.z; my[11] = q0.w;
    my[12] = q1.x; my[13] = q1.y; my[14] = q1.z; my[15] = q1.w;
    __syncthreads();
    const int t = threadIdx.x;
    float s = 0.f;
#pragma unroll
    for (int gg = 0; gg < 16; ++gg) s += red[gg * 256 + t];
    partials[(size_t)t * SPMM_GRID + blockIdx.x] = s;
  }
}

__global__ __launch_bounds__(256)
void k_bnred(const float* __restrict__ partials, float* __restrict__ stat) {
  __shared__ float s[256];
  const int slot = blockIdx.x;
  float v = 0.f;
  for (int i = threadIdx.x; i < SPMM_GRID; i += 256)
    v += partials[(size_t)slot * SPMM_GRID + i];
  s[threadIdx.x] = v;
  __syncthreads();
  for (int off = 128; off; off >>= 1) {
    if (threadIdx.x < off) s[threadIdx.x] += s[threadIdx.x + off];
    __syncthreads();
  }
  if (threadIdx.x == 0) stat[slot] = s[0];
}

__global__ __launch_bounds__(256)
void k_bnfin(const float* __restrict__ stat, float* __restrict__ ss,
             const float* __restrict__ gamma, const float* __restrict__ beta) {
  __shared__ float tot[256];            // [kind*128 + c]
  const int t = threadIdx.x;
  const float s = stat[t];
  const int lane16 = t >> 4, q = t & 15;
  const int c = lane16 * 8 + (q & 7), kind = q >> 3;
  tot[kind * 128 + c] = s;
  __syncthreads();
  if (t < 128) {
    const float m = tot[t] * (1.0f / NN);
    const float var = tot[128 + t] * (1.0f / NN) - m * m;
    const float rs = rsqrtf(var + BN_EPS);
    const float sc = rs * gamma[t];
    ss[t] = sc;
    ss[128 + t] = beta[t] - m * sc;
  }
}

__global__ __launch_bounds__(256)
void k_bn(float* __restrict__ h, float* __restrict__ out,
          const float* __restrict__ ss) {
  const int i4 = blockIdx.x * 256 + threadIdx.x;   // exactly N*D/4 threads
  const int c4 = (i4 & 31) * 4;
  const float4 sc = *(const float4*)&ss[c4];
  const float4 sh = *(const float4*)&ss[128 + c4];
  float4 hv = ((const float4*)h)[i4];
  float4 o;
  o.x = fmaf(hv.x, sc.x, sh.x);
  o.y = fmaf(hv.y, sc.y, sh.y);
  o.z = fmaf(hv.z, sc.z, sh.z);
  o.w = fmaf(hv.w, sc.w, sh.w);
  ((float4*)h)[i4] = o;
  float4 po = ((float4*)out)[i4];
  po.x += o.x; po.y += o.y; po.z += o.z; po.w += o.w;
  ((float4*)out)[i4] = po;
}

extern "C" void kernel_launch(void* const* d_in, const int* in_sizes, int n_in,
                              void* d_out, int out_size, void* d_ws, size_t ws_size,
                              hipStream_t stream) {
  const float* x = (const float*)d_in[0];
  const int* ei = (const int*)d_in[1];
  const float* W = (const float*)d_in[2];
  const float* b = (const float*)d_in[3];
  const float* gamma = (const float*)d_in[4];
  const float* beta = (const float*)d_in[5];
  float* out = (float*)d_out;
  const int* srcv = ei;
  const int* dstv = ei + EE;

  char* w = (char*)d_ws;
  int* rowptr = (int*)w;     w += (size_t)NPAD * 4;
  float* dinv = (float*)w;   w += (size_t)NPAD * 4;
  int* bcnt = (int*)w;       w += (size_t)NB * 16 * 4;
  int* bbase = (int*)w;      w += (size_t)2048 * 4;
  int* col = (int*)w;        w += (size_t)EE * 4;
  float* ss = (float*)w;     w += 256 * 4;
  float* stat = (float*)w;   w += 256 * 4;
  unsigned short* Wt = (unsigned short*)w; w += (size_t)3 * DD * DD * 2;
  // bstore (CSR-build only) aliases partials (spmm/bnred only)
  unsigned* bstore = (unsigned*)w;
  float* partials = (float*)w; w += (size_t)NB * CAP * 4;  // 9.6 MB >= 6.4 MB
  float* bufA = (float*)w;   w += (size_t)NN * DD * 4;     // h (fp32)
  unsigned short* hsb = (unsigned short*)w;                // hs (bf16)

  hipMemsetAsync(bcnt, 0, (size_t)NB * 16 * 4, stream);
  hipMemcpyAsync(out, x, (size_t)NN * DD * sizeof(float),
                 hipMemcpyDeviceToDevice, stream);

  k_bin<<<(EE + 255) / 256, 256, 0, stream>>>(srcv, dstv, bcnt, bstore);
  k_bscan<<<1, 1024, 0, stream>>>(bcnt, bbase);
  k_csr<<<NB, 256, 0, stream>>>(bstore, bcnt, bbase, rowptr, col, dinv);
  k_wt<<<3, 256, 0, stream>>>(W, Wt);

  const float* hcur = x;
  for (int l = 0; l < 3; ++l) {
    k_gemm<<<GEMM_GRID, 256, 0, stream>>>(hcur, Wt + (size_t)l * DD * DD,
                                          dinv, hsb);
    if (l < 2) {
      k_spmm<<<SPMM_GRID, 256, 0, stream>>>(hsb, rowptr, col, dinv,
                                            b + l * DD, bufA, nullptr,
                                            partials, 0);
      k_bnred<<<256, 256, 0, stream>>>(partials, stat);
      k_bnfin<<<1, 256, 0, stream>>>(stat, ss, gamma + l * DD, beta + l * DD);
      k_bn<<<(NN * DD / 4) / 256, 256, 0, stream>>>(bufA, out, ss);
      hcur = bufA;
    } else {
      k_spmm<<<SPMM_GRID, 256, 0, stream>>>(hsb, rowptr, col, dinv,
                                            b + l * DD, nullptr, out,
                                            nullptr, 1);
    }
  }
}